// Round 2
// baseline (391.560 us; speedup 1.0000x reference)
//
#include <hip/hip_runtime.h>
#include <hip/hip_bf16.h>

typedef unsigned short u16;
typedef unsigned int u32;
typedef unsigned long long u64;
typedef __attribute__((ext_vector_type(8))) short short8;
typedef __attribute__((ext_vector_type(4))) float float4v;

#define B_DIM 64
#define H_DIM 2048
#define K_DIM 256
#define NTHR  256

// workspace layout (bytes)
#define WS_WBF   0ull                         // 2048*2048*2 = 8388608
#define WS_AQ    (8388608ull)                 // 128*2048*2  = 524288
#define WS_Q     (WS_AQ + 524288ull)          // 64*2048*4   = 524288
#define WS_KN2   (WS_Q + 524288ull)           // 16384*4
#define WS_DOTS  (WS_KN2 + 65536ull)          // 16384*4
#define WS_KBF   (WS_DOTS + 65536ull)         // 16384*2048*2 = 67108864

__device__ __forceinline__ u16 f2bf(float f) {
    unsigned int u = __float_as_uint(f);
    unsigned int r = (u + 0x7fffu + ((u >> 16) & 1u)) >> 16;
    return (u16)r;
}

__device__ __forceinline__ u64 pack4(float4v v) {
    u64 a0 = f2bf(v.x), a1 = f2bf(v.y), a2 = f2bf(v.z), a3 = f2bf(v.w);
    return a0 | (a1 << 16) | (a2 << 32) | (a3 << 48);
}

// async global->LDS 16B/lane; lds dest = wave-uniform base + lane*16
__device__ __forceinline__ void llds16(const u16* g, u16* l) {
    __builtin_amdgcn_global_load_lds(
        (__attribute__((address_space(1))) void*)g,
        (__attribute__((address_space(3))) void*)l, 16, 0, 0);
}

// ---- gemm0 (q += in@W^T): 128-tile 2-barrier structure, now 16-way split-K
// (ksplit 0..15, 4 K-steps each). LDS XOR swizzle proven conflict-free.
__device__ __forceinline__ void gemm0_tile(const u16* __restrict__ Aq, const u16* __restrict__ Wb,
                                           float* __restrict__ qout, u16* As, u16* Bs,
                                           int nt, int ksplit) {
    const int tid = threadIdx.x;
    const int wave = tid >> 6, lane = tid & 63;
    const int l15 = lane & 15, qd = lane >> 4;
    const int wm = wave >> 1, wn = wave & 1;
    const int n0 = nt * 128;
    const int grow = lane >> 2;
    const int gcol = (((lane & 3) ^ ((lane >> 3) & 3)) * 8);
    const int sw = (l15 >> 1) & 3;
    float4v acc[4][4] = {};
    const int kb0 = ksplit * 128;
    for (int kk = 0; kk < 4; ++kk) {
        const int k0 = kb0 + kk * 32;
        #pragma unroll
        for (int i = 0; i < 2; ++i) {
            const int r = wave * 32 + i * 16;
            llds16(Wb + (size_t)(n0 + r + grow) * H_DIM + k0 + gcol, &Bs[r * 32]);
            llds16(Aq + (size_t)(r + grow) * H_DIM + k0 + gcol, &As[r * 32]);
        }
        __syncthreads();
        short8 af[4], bf_[4];
        #pragma unroll
        for (int mi = 0; mi < 4; ++mi)
            af[mi] = *(const short8*)&As[(wm * 64 + mi * 16 + l15) * 32 + ((qd ^ sw) * 8)];
        #pragma unroll
        for (int ni = 0; ni < 4; ++ni)
            bf_[ni] = *(const short8*)&Bs[(wn * 64 + ni * 16 + l15) * 32 + ((qd ^ sw) * 8)];
        #pragma unroll
        for (int mi = 0; mi < 4; ++mi)
            #pragma unroll
            for (int ni = 0; ni < 4; ++ni)
                acc[mi][ni] = __builtin_amdgcn_mfma_f32_16x16x32_bf16(af[mi], bf_[ni], acc[mi][ni], 0, 0, 0);
        __syncthreads();
    }
    const int n0w = n0 + wn * 64;
    if (wm == 0) {
        #pragma unroll
        for (int mi = 0; mi < 4; ++mi)
            #pragma unroll
            for (int reg = 0; reg < 4; ++reg) {
                const int m = mi * 16 + qd * 4 + reg;   // 0..63 == b
                #pragma unroll
                for (int ni = 0; ni < 4; ++ni)
                    atomicAdd(&qout[m * H_DIM + n0w + ni * 16 + l15], acc[mi][ni][reg]);
            }
    }
}

// ---- k1: W->bf16 + kb->bf16 (fused: no deps, runs first) + input->Aq + q=bias
//          + zero kn2/dots (grid 4096) ----
__global__ __launch_bounds__(256) void prep_kernel(
        const float* __restrict__ W, const float* __restrict__ kb,
        const float* __restrict__ input, const float* __restrict__ bias,
        u16* __restrict__ Wb, u16* __restrict__ Kbf,
        u16* __restrict__ Aq, float* __restrict__ q,
        float* __restrict__ kn2, float* __restrict__ dots) {
    const int gid = blockIdx.x * NTHR + threadIdx.x;   // 0..1048575
    ((u64*)Wb)[gid] = pack4(((const float4v*)W)[gid]);
    {
        const float4v* s4 = (const float4v*)kb;
        u64* d8 = (u64*)Kbf;
        #pragma unroll
        for (int i = 0; i < 8; ++i)
            d8[gid + i * 1048576] = pack4(s4[gid + i * 1048576]);
    }
    if (gid < 65536) {
        u64 v = 0;
        if (gid < 32768) v = pack4(((const float4v*)input)[gid]);
        ((u64*)Aq)[gid] = v;
    }
    if (gid < 32768)
        ((float4v*)q)[gid] = ((const float4v*)bias)[gid & 511];
    if (gid < 4096) ((float4v*)kn2)[gid] = float4v{0.f, 0.f, 0.f, 0.f};
    else if (gid < 8192) ((float4v*)dots)[gid - 4096] = float4v{0.f, 0.f, 0.f, 0.f};
}

// ---- k2: gemm0 only (grid 256 = 16 nt x 16 ksplit) ----
__global__ __launch_bounds__(256, 4) void mid_kernel(
        const u16* __restrict__ Aq, const u16* __restrict__ Wb, float* __restrict__ q) {
    __shared__ __align__(16) u16 As[128 * 32];
    __shared__ __align__(16) u16 Bs[128 * 32];
    gemm0_tile(Aq, Wb, q, As, Bs, blockIdx.x & 15, blockIdx.x >> 4);
}

// ---- k3: big GEMM, 256x256 tile, BK=32, 8 waves (2M x 4N), 4-deep LDS ring.
// NEW schedule: 1 barrier/tile, counted lgkmcnt, cross-tile fragment prefetch.
// Per tile t (regs bfC/a0C current, bfN/a0N next; unroll-2 for static swap):
//   stageA(t+3); lgkm(0) [drain bfC/a0C reads issued last tile];
//   MFMA0 x16 (a0C,bfC -> acc[0..3]);
//   issue a1 reads INTO a0C regs (slot t, WAR on MFMA0 srcs = hazard-nop only);
//   issue bfN/a0N reads (slot t+1, published one tile early);
//   stageB(t+3); lgkm(8) [a1 done, next 8 in flight];
//   MFMA1 x16 (a0C=a1,bfC -> acc[4..7]); vmcnt(4); barrier.
// All LDS reads execute under MFMA compute; never vmcnt(0)/lgkm(0)-drain mid-loop.
// Ring safety: stage(t+3) writes slot (t-1)&3, whose reads finished before the
// end-of-(t-1) barrier; slot t+1 published by vmcnt(4)+barrier at end of t-1.
#define TILE_BODY(T, bfC, a0C, bfN, a0N)                                        \
  {                                                                             \
    const int t_ = (T);                                                         \
    const u16* As_ = lds + (t_ & 3) * 16384;                                    \
    const u16* Bs_ = As_ + 8192;                                                \
    if (t_ + 3 < 64) stageA(t_ + 3);                                            \
    asm volatile("s_waitcnt lgkmcnt(0)" ::: "memory");                          \
    __builtin_amdgcn_sched_barrier(0);                                          \
    __builtin_amdgcn_s_setprio(1);                                              \
    _Pragma("unroll") for (int mi = 0; mi < 4; ++mi)                            \
      _Pragma("unroll") for (int ni = 0; ni < 4; ++ni)                          \
        acc[mi][ni] = __builtin_amdgcn_mfma_f32_16x16x32_bf16(a0C[mi], bfC[ni], acc[mi][ni], 0, 0, 0); \
    __builtin_amdgcn_s_setprio(0);                                              \
    __builtin_amdgcn_sched_barrier(0);                                          \
    _Pragma("unroll") for (int mi = 0; mi < 4; ++mi)                            \
        a0C[mi] = *(const short8*)&As_[aoff + (4 + mi) * 512];                  \
    if (t_ + 1 < 64) {                                                          \
      const u16* Asn_ = lds + ((t_ + 1) & 3) * 16384;                           \
      const u16* Bsn_ = Asn_ + 8192;                                            \
      _Pragma("unroll") for (int ni = 0; ni < 4; ++ni)                          \
          bfN[ni] = *(const short8*)&Bsn_[boff + ni * 512];                     \
      _Pragma("unroll") for (int mi = 0; mi < 4; ++mi)                          \
          a0N[mi] = *(const short8*)&Asn_[aoff + mi * 512];                     \
    }                                                                           \
    if (t_ + 3 < 64) stageB(t_ + 3);                                            \
    if (t_ + 1 < 64) { asm volatile("s_waitcnt lgkmcnt(8)" ::: "memory"); }     \
    else             { asm volatile("s_waitcnt lgkmcnt(0)" ::: "memory"); }     \
    __builtin_amdgcn_sched_barrier(0);                                          \
    __builtin_amdgcn_s_setprio(1);                                              \
    _Pragma("unroll") for (int mi = 0; mi < 4; ++mi)                            \
      _Pragma("unroll") for (int ni = 0; ni < 4; ++ni)                          \
        acc[4 + mi][ni] = __builtin_amdgcn_mfma_f32_16x16x32_bf16(a0C[mi], bfC[ni], acc[4 + mi][ni], 0, 0, 0); \
    __builtin_amdgcn_s_setprio(0);                                              \
    __builtin_amdgcn_sched_barrier(0);                                          \
    if (t_ <= 60) { asm volatile("s_waitcnt vmcnt(4)" ::: "memory"); }          \
    else          { asm volatile("s_waitcnt vmcnt(0)" ::: "memory"); }          \
    __builtin_amdgcn_s_barrier();                                               \
  }

__global__ __launch_bounds__(512, 2) void gemm_kernel(
        const u16* __restrict__ Kbf, const u16* __restrict__ Wb,
        const float* __restrict__ bias, const float* __restrict__ q,
        float* __restrict__ kn2, float* __restrict__ dots) {
    extern __shared__ __align__(16) u16 lds[];   // 4 slots x (A 8192 + B 8192) u16 = 128 KiB
    const int tid = threadIdx.x;
    const int wave = tid >> 6, lane = tid & 63;
    const int l15 = lane & 15, qd = lane >> 4;
    const int wm = wave >> 2, wn = wave & 3;
    const int nt = blockIdx.x & 7, mt = blockIdx.x >> 3;  // nt==XCD: B-panel L2-resident
    const int m0 = mt * 256, n0 = nt * 256;
    const int grow = wave * 16 + (lane >> 2);             // staging row within 128-row half
    const int gcol = (((lane & 3) ^ ((lane >> 3) & 3)) * 8);  // source-side XOR swizzle
    const int sw = (l15 >> 1) & 3;                        // read-side XOR swizzle

    const u16* srcA = Kbf + (size_t)(m0 + grow) * H_DIM + gcol;
    const u16* srcB = Wb + (size_t)(n0 + grow) * H_DIM + gcol;
    u16* dstBase = lds + wave * 512;                      // wave-uniform LDS dest base

    auto stageA = [&](int t) {
        u16* d = dstBase + (t & 3) * 16384;
        const u16* s = srcA + t * 32;
        llds16(s, d);                                     // rows 0..127
        llds16(s + (size_t)128 * H_DIM, d + 4096);        // rows 128..255
    };
    auto stageB = [&](int t) {
        u16* d = dstBase + (t & 3) * 16384 + 8192;
        const u16* s = srcB + t * 32;
        llds16(s, d);
        llds16(s + (size_t)128 * H_DIM, d + 4096);
    };

    const int aoff = (wm * 128 + l15) * 32 + ((qd ^ sw) * 8);
    const int boff = (wn * 64 + l15) * 32 + ((qd ^ sw) * 8);

    float4v acc[8][4] = {};
    short8 bf0[4], a00[4], bf1[4], a01[4];

    // prologue: stage tiles 0,1,2; land 0,1; publish; preload tile-0 phase0 frags
    stageA(0); stageB(0); stageA(1); stageB(1); stageA(2); stageB(2);
    asm volatile("s_waitcnt vmcnt(4)" ::: "memory");      // tiles 0,1 landed
    __builtin_amdgcn_sched_barrier(0);
    __builtin_amdgcn_s_barrier();                         // publish slots 0,1
    {
        const u16* As0 = lds;
        const u16* Bs0 = lds + 8192;
        #pragma unroll
        for (int ni = 0; ni < 4; ++ni) bf0[ni] = *(const short8*)&Bs0[boff + ni * 512];
        #pragma unroll
        for (int mi = 0; mi < 4; ++mi) a00[mi] = *(const short8*)&As0[aoff + mi * 512];
    }

    for (int t = 0; t < 64; t += 2) {
        TILE_BODY(t,     bf0, a00, bf1, a01);
        TILE_BODY(t + 1, bf1, a01, bf0, a00);
    }

    // ---- fused epilogue: per-row sum(y^2), sum(y*q) with bias add ----
    const int n0w = n0 + wn * 64;
    float bv[4];
    #pragma unroll
    for (int ni = 0; ni < 4; ++ni) bv[ni] = bias[n0w + ni * 16 + l15];
    #pragma unroll
    for (int mi = 0; mi < 8; ++mi)
        #pragma unroll
        for (int reg = 0; reg < 4; ++reg) {
            const int mloc = mi * 16 + qd * 4 + reg;          // 0..127 within wave tile
            const int mg = m0 + wm * 128 + mloc;              // global row = k*64+b
            const float* qrow = q + (mloc & 63) * H_DIM;      // b = mg & 63 = mloc & 63
            float s2 = 0.f, sd = 0.f;
            #pragma unroll
            for (int ni = 0; ni < 4; ++ni) {
                const float y = acc[mi][ni][reg] + bv[ni];
                const float qv = qrow[n0w + ni * 16 + l15];
                s2 += y * y; sd += y * qv;
            }
            #pragma unroll
            for (int off = 1; off < 16; off <<= 1) {
                s2 += __shfl_xor(s2, off);
                sd += __shfl_xor(sd, off);
            }
            if (l15 == 0) {
                atomicAdd(&kn2[mg], s2);
                atomicAdd(&dots[mg], sd);
            }
        }
}

// ---- k4: per-b softmax (recomputed per slice-block) + out = input + sum_k attn*kb ----
__global__ __launch_bounds__(256) void final_kernel(
        const float* __restrict__ input, const u16* __restrict__ Kbf,
        const float* __restrict__ q, const float* __restrict__ kn2,
        const float* __restrict__ dots, float* __restrict__ out) {
    __shared__ float sm[K_DIM];
    __shared__ float buf[4];
    const int b = blockIdx.x >> 2, hc = blockIdx.x & 3, tid = threadIdx.x;
    // qn
    float s = 0.f;
    #pragma unroll
    for (int i = 0; i < 8; ++i) {
        float v = q[b * H_DIM + i * 256 + tid];
        s += v * v;
    }
    #pragma unroll
    for (int o = 32; o >= 1; o >>= 1) s += __shfl_xor(s, o);
    if ((tid & 63) == 0) buf[tid >> 6] = s;
    __syncthreads();
    const float qn = fmaxf(sqrtf(buf[0] + buf[1] + buf[2] + buf[3]), 1e-8f);
    __syncthreads();
    // score + softmax over k (k == tid)
    const float kn = fmaxf(sqrtf(kn2[tid * B_DIM + b]), 1e-8f);
    const float sc = dots[tid * B_DIM + b] / (qn * kn);
    float mx = sc;
    #pragma unroll
    for (int o = 32; o >= 1; o >>= 1) mx = fmaxf(mx, __shfl_xor(mx, o));
    if ((tid & 63) == 0) buf[tid >> 6] = mx;
    __syncthreads();
    mx = fmaxf(fmaxf(buf[0], buf[1]), fmaxf(buf[2], buf[3]));
    __syncthreads();
    const float e = expf(sc - mx);
    float se = e;
    #pragma unroll
    for (int o = 32; o >= 1; o >>= 1) se += __shfl_xor(se, o);
    if ((tid & 63) == 0) buf[tid >> 6] = se;
    __syncthreads();
    se = buf[0] + buf[1] + buf[2] + buf[3];
    sm[tid] = e / se;
    __syncthreads();
    // weighted sum for this block's 512-float h-slice
    const u32* base = (const u32*)Kbf;
    const int h2 = hc * 256 + tid;             // u32 unit, 0..1023
    float s0 = 0.f, s1 = 0.f;
    #pragma unroll 8
    for (int k = 0; k < K_DIM; ++k) {
        const u32 p = base[(size_t)(k * B_DIM + b) * (H_DIM / 2) + h2];
        const float a = sm[k];
        s0 += a * __uint_as_float(p << 16);
        s1 += a * __uint_as_float(p & 0xffff0000u);
    }
    const int h = h2 * 2;
    float2 iv = *(const float2*)&input[(size_t)b * H_DIM + h];
    float2 r; r.x = iv.x + s0; r.y = iv.y + s1;
    *(float2*)&out[(size_t)b * H_DIM + h] = r;
}

extern "C" void kernel_launch(void* const* d_in, const int* in_sizes, int n_in,
                              void* d_out, int out_size, void* d_ws, size_t ws_size,
                              hipStream_t stream) {
    const float* input = (const float*)d_in[0];
    const float* kb    = (const float*)d_in[1];
    const float* W     = (const float*)d_in[2];
    const float* bias  = (const float*)d_in[3];
    float* out = (float*)d_out;
    char* ws = (char*)d_ws;

    u16*   Wb   = (u16*)(ws + WS_WBF);
    u16*   Aq   = (u16*)(ws + WS_AQ);
    float* q    = (float*)(ws + WS_Q);
    float* kn2  = (float*)(ws + WS_KN2);
    float* dots = (float*)(ws + WS_DOTS);
    u16*   Kbf  = (u16*)(ws + WS_KBF);

    static int lds_set = 0;
    if (!lds_set) {
        hipFuncSetAttribute((const void*)gemm_kernel,
                            hipFuncAttributeMaxDynamicSharedMemorySize, 131072);
        lds_set = 1;
    }

    prep_kernel<<<4096, NTHR, 0, stream>>>(W, kb, input, bias, Wb, Kbf, Aq, q, kn2, dots);
    mid_kernel<<<256, NTHR, 0, stream>>>(Aq, Wb, q);
    gemm_kernel<<<512, 512, 131072, stream>>>(Kbf, Wb, bias, q, kn2, dots);
    final_kernel<<<256, NTHR, 0, stream>>>(input, Kbf, q, kn2, dots, out);
}

// Round 3
// 372.507 us; speedup vs baseline: 1.0511x; 1.0511x over previous
//
#include <hip/hip_runtime.h>
#include <hip/hip_bf16.h>

typedef unsigned short u16;
typedef unsigned int u32;
typedef unsigned long long u64;
typedef __attribute__((ext_vector_type(8))) short short8;
typedef __attribute__((ext_vector_type(4))) float float4v;

#define B_DIM 64
#define H_DIM 2048
#define K_DIM 256
#define NTHR  256

// workspace layout (bytes)
#define WS_WBF   0ull                         // 2048*2048*2 = 8388608
#define WS_AQ    (8388608ull)                 // 128*2048*2  = 524288
#define WS_Q     (WS_AQ + 524288ull)          // 64*2048*4   = 524288
#define WS_KN2   (WS_Q + 524288ull)           // 16384*4
#define WS_DOTS  (WS_KN2 + 65536ull)          // 16384*4
#define WS_KBF   (WS_DOTS + 65536ull)         // 16384*2048*2 = 67108864

__device__ __forceinline__ u16 f2bf(float f) {
    unsigned int u = __float_as_uint(f);
    unsigned int r = (u + 0x7fffu + ((u >> 16) & 1u)) >> 16;
    return (u16)r;
}

__device__ __forceinline__ u64 pack4(float4v v) {
    u64 a0 = f2bf(v.x), a1 = f2bf(v.y), a2 = f2bf(v.z), a3 = f2bf(v.w);
    return a0 | (a1 << 16) | (a2 << 32) | (a3 << 48);
}

// async global->LDS 16B/lane; lds dest = wave-uniform base + lane*16
__device__ __forceinline__ void llds16(const u16* g, const u16* l) {
    __builtin_amdgcn_global_load_lds(
        (__attribute__((address_space(1))) void*)g,
        (__attribute__((address_space(3))) void*)l, 16, 0, 0);
}

// ---- gemm0 (q += in@W^T): 128-tile 2-barrier structure, 4-way split-K ----
__device__ __forceinline__ void gemm0_tile(const u16* __restrict__ Aq, const u16* __restrict__ Wb,
                                           float* __restrict__ qout, u16* As, u16* Bs,
                                           int nt, int ksplit) {
    const int tid = threadIdx.x;
    const int wave = tid >> 6, lane = tid & 63;
    const int l15 = lane & 15, qd = lane >> 4;
    const int wm = wave >> 1, wn = wave & 1;
    const int n0 = nt * 128;
    const int grow = lane >> 2;
    const int gcol = (((lane & 3) ^ ((lane >> 3) & 3)) * 8);
    const int sw = (l15 >> 1) & 3;
    float4v acc[4][4] = {};
    const int kb0 = ksplit * 512;
    for (int kk = 0; kk < 16; ++kk) {
        const int k0 = kb0 + kk * 32;
        #pragma unroll
        for (int i = 0; i < 2; ++i) {
            const int r = wave * 32 + i * 16;
            llds16(Wb + (size_t)(n0 + r + grow) * H_DIM + k0 + gcol, &Bs[r * 32]);
            llds16(Aq + (size_t)(r + grow) * H_DIM + k0 + gcol, &As[r * 32]);
        }
        __syncthreads();
        short8 af[4], bf_[4];
        #pragma unroll
        for (int mi = 0; mi < 4; ++mi)
            af[mi] = *(const short8*)&As[(wm * 64 + mi * 16 + l15) * 32 + ((qd ^ sw) * 8)];
        #pragma unroll
        for (int ni = 0; ni < 4; ++ni)
            bf_[ni] = *(const short8*)&Bs[(wn * 64 + ni * 16 + l15) * 32 + ((qd ^ sw) * 8)];
        #pragma unroll
        for (int mi = 0; mi < 4; ++mi)
            #pragma unroll
            for (int ni = 0; ni < 4; ++ni)
                acc[mi][ni] = __builtin_amdgcn_mfma_f32_16x16x32_bf16(af[mi], bf_[ni], acc[mi][ni], 0, 0, 0);
        __syncthreads();
    }
    const int n0w = n0 + wn * 64;
    if (wm == 0) {
        #pragma unroll
        for (int mi = 0; mi < 4; ++mi)
            #pragma unroll
            for (int reg = 0; reg < 4; ++reg) {
                const int m = mi * 16 + qd * 4 + reg;   // 0..63 == b
                #pragma unroll
                for (int ni = 0; ni < 4; ++ni)
                    atomicAdd(&qout[m * H_DIM + n0w + ni * 16 + l15], acc[mi][ni][reg]);
            }
    }
}

// ---- k1: W->bf16 + input->Aq + q=bias + zero kn2/dots (grid 4096) ----
__global__ __launch_bounds__(256) void prep_kernel(
        const float* __restrict__ W, const float* __restrict__ input,
        const float* __restrict__ bias, u16* __restrict__ Wb,
        u16* __restrict__ Aq, float* __restrict__ q,
        float* __restrict__ kn2, float* __restrict__ dots) {
    const int gid = blockIdx.x * NTHR + threadIdx.x;   // 0..1048575
    ((u64*)Wb)[gid] = pack4(((const float4v*)W)[gid]);
    if (gid < 65536) {
        u64 v = 0;
        if (gid < 32768) v = pack4(((const float4v*)input)[gid]);
        ((u64*)Aq)[gid] = v;
    }
    if (gid < 32768)
        ((float4v*)q)[gid] = ((const float4v*)bias)[gid & 511];
    if (gid < 4096) ((float4v*)kn2)[gid] = float4v{0.f, 0.f, 0.f, 0.f};
    else if (gid < 8192) ((float4v*)dots)[gid - 4096] = float4v{0.f, 0.f, 0.f, 0.f};
}

// ---- k2: blocks 0-63 gemm0 (q += in@W^T, split-K atomics); blocks 64+ kb->bf16
// (convert overlaps gemm0 on the GPU — measured faster than fusing into prep) ----
__global__ __launch_bounds__(256, 4) void mid_kernel(
        const float* __restrict__ kb, const u16* __restrict__ Aq,
        const u16* __restrict__ Wb, float* __restrict__ q, u16* __restrict__ Kbf) {
    __shared__ __align__(16) u16 As[128 * 32];
    __shared__ __align__(16) u16 Bs[128 * 32];
    const int bid = blockIdx.x;
    if (bid < 64) {
        gemm0_tile(Aq, Wb, q, As, Bs, bid & 15, bid >> 4);
    } else {
        const float4v* s4 = (const float4v*)kb;
        u64* d8 = (u64*)Kbf;
        for (int i = (bid - 64) * NTHR + threadIdx.x; i < 8388608; i += 960 * NTHR)
            d8[i] = pack4(s4[i]);
    }
}

// ---- k3: big GEMM, 256x256 tile, BK=64, 8 waves (2M x 4N), 2-deep LDS dbuf,
// m201-style 4-phase schedule. Per phase: {ds_read quadrant frags + stage-issue;
// barrier; lgkm(0); setprio(1); 16 MFMA; setprio(0); barrier}. Reads issued
// pre-barrier drain on the LDS pipe WHILE the MFMA cluster runs (per-wave lgkm
// waits stagger by queue order) -> LDS/MFMA overlap instead of alternation.
// A staged in ph0, B in ph1; single vmcnt(0) at iter end waits loads issued
// >=2 phases (~1200cyc) earlier. LDS rows are 128B; store granule g^(row&7)
// (via pre-swizzled global source col), read with same XOR -> <=2-way (free).
__global__ __launch_bounds__(512, 2) void gemm_kernel(
        const u16* __restrict__ Kbf, const u16* __restrict__ Wb,
        const float* __restrict__ bias, const float* __restrict__ q,
        float* __restrict__ kn2, float* __restrict__ dots) {
    extern __shared__ __align__(16) u16 lds[];   // 2 bufs x (A 256x64 + B 256x64) bf16 = 128 KiB
    const int tid = threadIdx.x;
    const int wave = tid >> 6, lane = tid & 63;
    const int l15 = lane & 15, qd = (lane >> 4) & 3;
    const int wm = wave >> 2, wn = wave & 3;
    const int nt = blockIdx.x & 7, mt = blockIdx.x >> 3;  // nt==XCD: B-panel L2-resident
    const int m0 = mt * 256, n0 = nt * 256;

    // staging: 512 thr x 16B = 8KB = 64 rows/load; wave-uniform LDS dest + lane*16
    const int srow = wave * 8 + (lane >> 3);               // row within 64-row load
    const int gsrc = (lane & 7) ^ ((lane >> 3) & 7);       // pre-swizzled col granule
    const u16* sA = Kbf + (size_t)(m0 + srow) * H_DIM + gsrc * 8;
    const u16* sB = Wb  + (size_t)(n0 + srow) * H_DIM + gsrc * 8;
    const int dst0 = wave * 512;                           // u16 units (1KB/wave)

    // frag read addressing (u16 units; row stride 64 u16 = 128B)
    const int sx = lane & 7;
    const int kq0 = (qd ^ sx) * 8;                         // k-half 0 granule byte/2
    const int kq1 = ((4 + qd) ^ sx) * 8;                   // k-half 1
    const int aBase = wm * 8192 + l15 * 64;                // A: wave wm owns rows wm*128..+127
    const int bBase = 16384 + (wn >> 1) * 8192 + ((wn & 1) * 64 + l15) * 64;

    float4v acc[8][4] = {};
    short8 aP[4], aQ[4], bP[4], bQ[4];

    // prologue: stage iter 0 into buf0 (8 loads), drain, publish
    llds16(sA,                          lds + dst0);
    llds16(sA + (size_t) 64 * H_DIM,    lds + 4096  + dst0);
    llds16(sA + (size_t)128 * H_DIM,    lds + 8192  + dst0);
    llds16(sA + (size_t)192 * H_DIM,    lds + 12288 + dst0);
    llds16(sB,                          lds + 16384 + dst0);
    llds16(sB + (size_t) 64 * H_DIM,    lds + 20480 + dst0);
    llds16(sB + (size_t)128 * H_DIM,    lds + 24576 + dst0);
    llds16(sB + (size_t)192 * H_DIM,    lds + 28672 + dst0);
    asm volatile("s_waitcnt vmcnt(0)" ::: "memory");
    __builtin_amdgcn_sched_barrier(0);
    __builtin_amdgcn_s_barrier();

    for (int it = 0; it < 32; ++it) {
        const u16* cur = lds + (it & 1) * 32768;
        const u16* nxt = lds + ((it + 1) & 1) * 32768;
        const bool st = (it < 31);
        const size_t c1 = (size_t)(it + 1) * 64;
        // ---- PH0: kh=0, m-lo; stage A(next) ----
        #pragma unroll
        for (int ni = 0; ni < 4; ++ni) bP[ni] = *(const short8*)&cur[bBase + ni * 1024 + kq0];
        #pragma unroll
        for (int mi = 0; mi < 4; ++mi) aP[mi] = *(const short8*)&cur[aBase + mi * 1024 + kq0];
        if (st) {
            llds16(sA + c1,                         nxt + dst0);
            llds16(sA + (size_t) 64 * H_DIM + c1,   nxt + 4096  + dst0);
            llds16(sA + (size_t)128 * H_DIM + c1,   nxt + 8192  + dst0);
            llds16(sA + (size_t)192 * H_DIM + c1,   nxt + 12288 + dst0);
        }
        __builtin_amdgcn_s_barrier();
        asm volatile("s_waitcnt lgkmcnt(0)" ::: "memory");
        __builtin_amdgcn_sched_barrier(0);
        __builtin_amdgcn_s_setprio(1);
        #pragma unroll
        for (int mi = 0; mi < 4; ++mi)
            #pragma unroll
            for (int ni = 0; ni < 4; ++ni)
                acc[mi][ni] = __builtin_amdgcn_mfma_f32_16x16x32_bf16(aP[mi], bP[ni], acc[mi][ni], 0, 0, 0);
        __builtin_amdgcn_s_setprio(0);
        __builtin_amdgcn_s_barrier();
        // ---- PH1: kh=0, m-hi; stage B(next) ----
        #pragma unroll
        for (int mi = 0; mi < 4; ++mi) aQ[mi] = *(const short8*)&cur[aBase + (4 + mi) * 1024 + kq0];
        if (st) {
            llds16(sB + c1,                         nxt + 16384 + dst0);
            llds16(sB + (size_t) 64 * H_DIM + c1,   nxt + 20480 + dst0);
            llds16(sB + (size_t)128 * H_DIM + c1,   nxt + 24576 + dst0);
            llds16(sB + (size_t)192 * H_DIM + c1,   nxt + 28672 + dst0);
        }
        __builtin_amdgcn_s_barrier();
        asm volatile("s_waitcnt lgkmcnt(0)" ::: "memory");
        __builtin_amdgcn_sched_barrier(0);
        __builtin_amdgcn_s_setprio(1);
        #pragma unroll
        for (int mi = 0; mi < 4; ++mi)
            #pragma unroll
            for (int ni = 0; ni < 4; ++ni)
                acc[4 + mi][ni] = __builtin_amdgcn_mfma_f32_16x16x32_bf16(aQ[mi], bP[ni], acc[4 + mi][ni], 0, 0, 0);
        __builtin_amdgcn_s_setprio(0);
        __builtin_amdgcn_s_barrier();
        // ---- PH2: kh=1, m-lo ----
        #pragma unroll
        for (int ni = 0; ni < 4; ++ni) bQ[ni] = *(const short8*)&cur[bBase + ni * 1024 + kq1];
        #pragma unroll
        for (int mi = 0; mi < 4; ++mi) aP[mi] = *(const short8*)&cur[aBase + mi * 1024 + kq1];
        __builtin_amdgcn_s_barrier();
        asm volatile("s_waitcnt lgkmcnt(0)" ::: "memory");
        __builtin_amdgcn_sched_barrier(0);
        __builtin_amdgcn_s_setprio(1);
        #pragma unroll
        for (int mi = 0; mi < 4; ++mi)
            #pragma unroll
            for (int ni = 0; ni < 4; ++ni)
                acc[mi][ni] = __builtin_amdgcn_mfma_f32_16x16x32_bf16(aP[mi], bQ[ni], acc[mi][ni], 0, 0, 0);
        __builtin_amdgcn_s_setprio(0);
        __builtin_amdgcn_s_barrier();
        // ---- PH3: kh=1, m-hi; iter-end vmcnt(0) (loads issued >=2 phases ago) ----
        #pragma unroll
        for (int mi = 0; mi < 4; ++mi) aQ[mi] = *(const short8*)&cur[aBase + (4 + mi) * 1024 + kq1];
        __builtin_amdgcn_s_barrier();
        asm volatile("s_waitcnt lgkmcnt(0)" ::: "memory");
        __builtin_amdgcn_sched_barrier(0);
        __builtin_amdgcn_s_setprio(1);
        #pragma unroll
        for (int mi = 0; mi < 4; ++mi)
            #pragma unroll
            for (int ni = 0; ni < 4; ++ni)
                acc[4 + mi][ni] = __builtin_amdgcn_mfma_f32_16x16x32_bf16(aQ[mi], bQ[ni], acc[4 + mi][ni], 0, 0, 0);
        __builtin_amdgcn_s_setprio(0);
        asm volatile("s_waitcnt vmcnt(0)" ::: "memory");
        __builtin_amdgcn_sched_barrier(0);
        __builtin_amdgcn_s_barrier();
    }

    // ---- fused epilogue: per-row sum(y^2), sum(y*q) with bias add ----
    const int n0w = n0 + wn * 64;
    float bv[4];
    #pragma unroll
    for (int ni = 0; ni < 4; ++ni) bv[ni] = bias[n0w + ni * 16 + l15];
    #pragma unroll
    for (int mi = 0; mi < 8; ++mi)
        #pragma unroll
        for (int reg = 0; reg < 4; ++reg) {
            const int mloc = mi * 16 + qd * 4 + reg;          // 0..127 within wave tile
            const int mg = m0 + wm * 128 + mloc;              // global row = k*64+b
            const float* qrow = q + (mloc & 63) * H_DIM;      // b = mg & 63 = mloc & 63
            float s2 = 0.f, sd = 0.f;
            #pragma unroll
            for (int ni = 0; ni < 4; ++ni) {
                const float y = acc[mi][ni][reg] + bv[ni];
                const float qv = qrow[n0w + ni * 16 + l15];
                s2 += y * y; sd += y * qv;
            }
            #pragma unroll
            for (int off = 1; off < 16; off <<= 1) {
                s2 += __shfl_xor(s2, off);
                sd += __shfl_xor(sd, off);
            }
            if (l15 == 0) {
                atomicAdd(&kn2[mg], s2);
                atomicAdd(&dots[mg], sd);
            }
        }
}

// ---- k4: per-b softmax (recomputed per slice-block) + out = input + sum_k attn*kb ----
__global__ __launch_bounds__(256) void final_kernel(
        const float* __restrict__ input, const u16* __restrict__ Kbf,
        const float* __restrict__ q, const float* __restrict__ kn2,
        const float* __restrict__ dots, float* __restrict__ out) {
    __shared__ float sm[K_DIM];
    __shared__ float buf[4];
    const int b = blockIdx.x >> 2, hc = blockIdx.x & 3, tid = threadIdx.x;
    // qn
    float s = 0.f;
    #pragma unroll
    for (int i = 0; i < 8; ++i) {
        float v = q[b * H_DIM + i * 256 + tid];
        s += v * v;
    }
    #pragma unroll
    for (int o = 32; o >= 1; o >>= 1) s += __shfl_xor(s, o);
    if ((tid & 63) == 0) buf[tid >> 6] = s;
    __syncthreads();
    const float qn = fmaxf(sqrtf(buf[0] + buf[1] + buf[2] + buf[3]), 1e-8f);
    __syncthreads();
    // score + softmax over k (k == tid)
    const float kn = fmaxf(sqrtf(kn2[tid * B_DIM + b]), 1e-8f);
    const float sc = dots[tid * B_DIM + b] / (qn * kn);
    float mx = sc;
    #pragma unroll
    for (int o = 32; o >= 1; o >>= 1) mx = fmaxf(mx, __shfl_xor(mx, o));
    if ((tid & 63) == 0) buf[tid >> 6] = mx;
    __syncthreads();
    mx = fmaxf(fmaxf(buf[0], buf[1]), fmaxf(buf[2], buf[3]));
    __syncthreads();
    const float e = expf(sc - mx);
    float se = e;
    #pragma unroll
    for (int o = 32; o >= 1; o >>= 1) se += __shfl_xor(se, o);
    if ((tid & 63) == 0) buf[tid >> 6] = se;
    __syncthreads();
    se = buf[0] + buf[1] + buf[2] + buf[3];
    sm[tid] = e / se;
    __syncthreads();
    // weighted sum for this block's 512-float h-slice
    const u32* base = (const u32*)Kbf;
    const int h2 = hc * 256 + tid;             // u32 unit, 0..1023
    float s0 = 0.f, s1 = 0.f;
    #pragma unroll 8
    for (int k = 0; k < K_DIM; ++k) {
        const u32 p = base[(size_t)(k * B_DIM + b) * (H_DIM / 2) + h2];
        const float a = sm[k];
        s0 += a * __uint_as_float(p << 16);
        s1 += a * __uint_as_float(p & 0xffff0000u);
    }
    const int h = h2 * 2;
    float2 iv = *(const float2*)&input[(size_t)b * H_DIM + h];
    float2 r; r.x = iv.x + s0; r.y = iv.y + s1;
    *(float2*)&out[(size_t)b * H_DIM + h] = r;
}

extern "C" void kernel_launch(void* const* d_in, const int* in_sizes, int n_in,
                              void* d_out, int out_size, void* d_ws, size_t ws_size,
                              hipStream_t stream) {
    const float* input = (const float*)d_in[0];
    const float* kb    = (const float*)d_in[1];
    const float* W     = (const float*)d_in[2];
    const float* bias  = (const float*)d_in[3];
    float* out = (float*)d_out;
    char* ws = (char*)d_ws;

    u16*   Wb   = (u16*)(ws + WS_WBF);
    u16*   Aq   = (u16*)(ws + WS_AQ);
    float* q    = (float*)(ws + WS_Q);
    float* kn2  = (float*)(ws + WS_KN2);
    float* dots = (float*)(ws + WS_DOTS);
    u16*   Kbf  = (u16*)(ws + WS_KBF);

    static int lds_set = 0;
    if (!lds_set) {
        hipFuncSetAttribute((const void*)gemm_kernel,
                            hipFuncAttributeMaxDynamicSharedMemorySize, 131072);
        lds_set = 1;
    }

    prep_kernel<<<4096, NTHR, 0, stream>>>(W, input, bias, Wb, Aq, q, kn2, dots);
    mid_kernel<<<1024, NTHR, 0, stream>>>(kb, Aq, Wb, q, Kbf);
    gemm_kernel<<<512, 512, 131072, stream>>>(Kbf, Wb, bias, q, kn2, dots);
    final_kernel<<<256, NTHR, 0, stream>>>(input, Kbf, q, kn2, dots, out);
}

// Round 4
// 367.085 us; speedup vs baseline: 1.0667x; 1.0148x over previous
//
#include <hip/hip_runtime.h>
#include <hip/hip_bf16.h>

typedef unsigned short u16;
typedef unsigned int u32;
typedef unsigned long long u64;
typedef __attribute__((ext_vector_type(8))) short short8;
typedef __attribute__((ext_vector_type(4))) float float4v;

#define B_DIM 64
#define H_DIM 2048
#define K_DIM 256
#define NTHR  256

// workspace layout (bytes)
#define WS_WBF   0ull                         // 2048*2048*2 = 8388608
#define WS_AQ    (8388608ull)                 // 128*2048*2  = 524288
#define WS_Q     (WS_AQ + 524288ull)          // 64*2048*4   = 524288
#define WS_KN2   (WS_Q + 524288ull)           // 16384*4
#define WS_DOTS  (WS_KN2 + 65536ull)          // 16384*4
#define WS_KBF   (WS_DOTS + 65536ull)         // 16384*2048*2 = 67108864

__device__ __forceinline__ u16 f2bf(float f) {
    unsigned int u = __float_as_uint(f);
    unsigned int r = (u + 0x7fffu + ((u >> 16) & 1u)) >> 16;
    return (u16)r;
}

__device__ __forceinline__ u64 pack4(float4v v) {
    u64 a0 = f2bf(v.x), a1 = f2bf(v.y), a2 = f2bf(v.z), a3 = f2bf(v.w);
    return a0 | (a1 << 16) | (a2 << 32) | (a3 << 48);
}

// async global->LDS 16B/lane; lds dest = wave-uniform base + lane*16
__device__ __forceinline__ void llds16(const u16* g, const u16* l) {
    __builtin_amdgcn_global_load_lds(
        (__attribute__((address_space(1))) void*)g,
        (__attribute__((address_space(3))) void*)l, 16, 0, 0);
}

// ---- gemm0 (q += in@W^T): 128-tile 2-barrier structure, 4-way split-K ----
__device__ __forceinline__ void gemm0_tile(const u16* __restrict__ Aq, const u16* __restrict__ Wb,
                                           float* __restrict__ qout, u16* As, u16* Bs,
                                           int nt, int ksplit) {
    const int tid = threadIdx.x;
    const int wave = tid >> 6, lane = tid & 63;
    const int l15 = lane & 15, qd = lane >> 4;
    const int wm = wave >> 1, wn = wave & 1;
    const int n0 = nt * 128;
    const int grow = lane >> 2;
    const int gcol = (((lane & 3) ^ ((lane >> 3) & 3)) * 8);
    const int sw = (l15 >> 1) & 3;
    float4v acc[4][4] = {};
    const int kb0 = ksplit * 512;
    for (int kk = 0; kk < 16; ++kk) {
        const int k0 = kb0 + kk * 32;
        #pragma unroll
        for (int i = 0; i < 2; ++i) {
            const int r = wave * 32 + i * 16;
            llds16(Wb + (size_t)(n0 + r + grow) * H_DIM + k0 + gcol, &Bs[r * 32]);
            llds16(Aq + (size_t)(r + grow) * H_DIM + k0 + gcol, &As[r * 32]);
        }
        __syncthreads();
        short8 af[4], bf_[4];
        #pragma unroll
        for (int mi = 0; mi < 4; ++mi)
            af[mi] = *(const short8*)&As[(wm * 64 + mi * 16 + l15) * 32 + ((qd ^ sw) * 8)];
        #pragma unroll
        for (int ni = 0; ni < 4; ++ni)
            bf_[ni] = *(const short8*)&Bs[(wn * 64 + ni * 16 + l15) * 32 + ((qd ^ sw) * 8)];
        #pragma unroll
        for (int mi = 0; mi < 4; ++mi)
            #pragma unroll
            for (int ni = 0; ni < 4; ++ni)
                acc[mi][ni] = __builtin_amdgcn_mfma_f32_16x16x32_bf16(af[mi], bf_[ni], acc[mi][ni], 0, 0, 0);
        __syncthreads();
    }
    const int n0w = n0 + wn * 64;
    if (wm == 0) {
        #pragma unroll
        for (int mi = 0; mi < 4; ++mi)
            #pragma unroll
            for (int reg = 0; reg < 4; ++reg) {
                const int m = mi * 16 + qd * 4 + reg;   // 0..63 == b
                #pragma unroll
                for (int ni = 0; ni < 4; ++ni)
                    atomicAdd(&qout[m * H_DIM + n0w + ni * 16 + l15], acc[mi][ni][reg]);
            }
    }
}

// ---- k1: W->bf16 + input->Aq + q=bias + zero kn2/dots (grid 4096) ----
__global__ __launch_bounds__(256) void prep_kernel(
        const float* __restrict__ W, const float* __restrict__ input,
        const float* __restrict__ bias, u16* __restrict__ Wb,
        u16* __restrict__ Aq, float* __restrict__ q,
        float* __restrict__ kn2, float* __restrict__ dots) {
    const int gid = blockIdx.x * NTHR + threadIdx.x;   // 0..1048575
    ((u64*)Wb)[gid] = pack4(((const float4v*)W)[gid]);
    if (gid < 65536) {
        u64 v = 0;
        if (gid < 32768) v = pack4(((const float4v*)input)[gid]);
        ((u64*)Aq)[gid] = v;
    }
    if (gid < 32768)
        ((float4v*)q)[gid] = ((const float4v*)bias)[gid & 511];
    if (gid < 4096) ((float4v*)kn2)[gid] = float4v{0.f, 0.f, 0.f, 0.f};
    else if (gid < 8192) ((float4v*)dots)[gid - 4096] = float4v{0.f, 0.f, 0.f, 0.f};
}

// ---- k2: blocks 0-63 gemm0 (q += in@W^T, split-K atomics); blocks 64+ kb->bf16
// (convert overlaps gemm0 on the GPU — measured faster than fusing into prep) ----
__global__ __launch_bounds__(256, 4) void mid_kernel(
        const float* __restrict__ kb, const u16* __restrict__ Aq,
        const u16* __restrict__ Wb, float* __restrict__ q, u16* __restrict__ Kbf) {
    __shared__ __align__(16) u16 As[128 * 32];
    __shared__ __align__(16) u16 Bs[128 * 32];
    const int bid = blockIdx.x;
    if (bid < 64) {
        gemm0_tile(Aq, Wb, q, As, Bs, bid & 15, bid >> 4);
    } else {
        const float4v* s4 = (const float4v*)kb;
        u64* d8 = (u64*)Kbf;
        for (int i = (bid - 64) * NTHR + threadIdx.x; i < 8388608; i += 960 * NTHR)
            d8[i] = pack4(s4[i]);
    }
}

// ---- k3: big GEMM, 256x256 tile, BK=32, 8 waves (2M x 4N), 4-deep LDS ring.
// R2 schedule (measured best: 147us): 1 barrier/tile, counted lgkmcnt,
// cross-tile fragment prefetch, never vmcnt(0)/lgkm(0)-drain mid-loop.
#define TILE_BODY(T, bfC, a0C, bfN, a0N)                                        \
  {                                                                             \
    const int t_ = (T);                                                         \
    const u16* As_ = lds + (t_ & 3) * 16384;                                    \
    if (t_ + 3 < 64) stageA(t_ + 3);                                            \
    asm volatile("s_waitcnt lgkmcnt(0)" ::: "memory");                          \
    __builtin_amdgcn_sched_barrier(0);                                          \
    __builtin_amdgcn_s_setprio(1);                                              \
    _Pragma("unroll") for (int mi = 0; mi < 4; ++mi)                            \
      _Pragma("unroll") for (int ni = 0; ni < 4; ++ni)                          \
        acc[mi][ni] = __builtin_amdgcn_mfma_f32_16x16x32_bf16(a0C[mi], bfC[ni], acc[mi][ni], 0, 0, 0); \
    __builtin_amdgcn_s_setprio(0);                                              \
    __builtin_amdgcn_sched_barrier(0);                                          \
    _Pragma("unroll") for (int mi = 0; mi < 4; ++mi)                            \
        a0C[mi] = *(const short8*)&As_[aoff + (4 + mi) * 512];                  \
    if (t_ + 1 < 64) {                                                          \
      const u16* Asn_ = lds + ((t_ + 1) & 3) * 16384;                           \
      const u16* Bsn_ = Asn_ + 8192;                                            \
      _Pragma("unroll") for (int ni = 0; ni < 4; ++ni)                          \
          bfN[ni] = *(const short8*)&Bsn_[boff + ni * 512];                     \
      _Pragma("unroll") for (int mi = 0; mi < 4; ++mi)                          \
          a0N[mi] = *(const short8*)&Asn_[aoff + mi * 512];                     \
    }                                                                           \
    if (t_ + 3 < 64) stageB(t_ + 3);                                            \
    if (t_ + 1 < 64) { asm volatile("s_waitcnt lgkmcnt(8)" ::: "memory"); }     \
    else             { asm volatile("s_waitcnt lgkmcnt(0)" ::: "memory"); }     \
    __builtin_amdgcn_sched_barrier(0);                                          \
    __builtin_amdgcn_s_setprio(1);                                              \
    _Pragma("unroll") for (int mi = 0; mi < 4; ++mi)                            \
      _Pragma("unroll") for (int ni = 0; ni < 4; ++ni)                          \
        acc[4 + mi][ni] = __builtin_amdgcn_mfma_f32_16x16x32_bf16(a0C[mi], bfC[ni], acc[4 + mi][ni], 0, 0, 0); \
    __builtin_amdgcn_s_setprio(0);                                              \
    __builtin_amdgcn_sched_barrier(0);                                          \
    if (t_ <= 60) { asm volatile("s_waitcnt vmcnt(4)" ::: "memory"); }          \
    else          { asm volatile("s_waitcnt vmcnt(0)" ::: "memory"); }          \
    __builtin_amdgcn_s_barrier();                                               \
  }

__global__ __launch_bounds__(512, 2) void gemm_kernel(
        const u16* __restrict__ Kbf, const u16* __restrict__ Wb,
        const float* __restrict__ bias, const float* __restrict__ q,
        float* __restrict__ kn2, float* __restrict__ dots) {
    extern __shared__ __align__(16) u16 lds[];   // 4 slots x (A 8192 + B 8192) u16 = 128 KiB
    const int tid = threadIdx.x;
    const int wave = tid >> 6, lane = tid & 63;
    const int l15 = lane & 15, qd = lane >> 4;
    const int wm = wave >> 2, wn = wave & 3;
    const int nt = blockIdx.x & 7, mt = blockIdx.x >> 3;  // nt==XCD: B-panel L2-resident
    const int m0 = mt * 256, n0 = nt * 256;
    const int grow = wave * 16 + (lane >> 2);             // staging row within 128-row half
    const int gcol = (((lane & 3) ^ ((lane >> 3) & 3)) * 8);  // source-side XOR swizzle
    const int sw = (l15 >> 1) & 3;                        // read-side XOR swizzle

    const u16* srcA = Kbf + (size_t)(m0 + grow) * H_DIM + gcol;
    const u16* srcB = Wb + (size_t)(n0 + grow) * H_DIM + gcol;
    u16* dstBase = lds + wave * 512;                      // wave-uniform LDS dest base

    auto stageA = [&](int t) {
        u16* d = dstBase + (t & 3) * 16384;
        const u16* s = srcA + t * 32;
        llds16(s, d);                                     // rows 0..127
        llds16(s + (size_t)128 * H_DIM, d + 4096);        // rows 128..255
    };
    auto stageB = [&](int t) {
        u16* d = dstBase + (t & 3) * 16384 + 8192;
        const u16* s = srcB + t * 32;
        llds16(s, d);
        llds16(s + (size_t)128 * H_DIM, d + 4096);
    };

    const int aoff = (wm * 128 + l15) * 32 + ((qd ^ sw) * 8);
    const int boff = (wn * 64 + l15) * 32 + ((qd ^ sw) * 8);

    float4v acc[8][4] = {};
    short8 bf0[4], a00[4], bf1[4], a01[4];

    // prologue: stage tiles 0,1,2; land 0,1; publish; preload tile-0 phase0 frags
    stageA(0); stageB(0); stageA(1); stageB(1); stageA(2); stageB(2);
    asm volatile("s_waitcnt vmcnt(4)" ::: "memory");      // tiles 0,1 landed
    __builtin_amdgcn_sched_barrier(0);
    __builtin_amdgcn_s_barrier();                         // publish slots 0,1
    {
        const u16* As0 = lds;
        const u16* Bs0 = lds + 8192;
        #pragma unroll
        for (int ni = 0; ni < 4; ++ni) bf0[ni] = *(const short8*)&Bs0[boff + ni * 512];
        #pragma unroll
        for (int mi = 0; mi < 4; ++mi) a00[mi] = *(const short8*)&As0[aoff + mi * 512];
    }

    for (int t = 0; t < 64; t += 2) {
        TILE_BODY(t,     bf0, a00, bf1, a01);
        TILE_BODY(t + 1, bf1, a01, bf0, a00);
    }

    // ---- fused epilogue: per-row sum(y^2), sum(y*q) with bias add ----
    const int n0w = n0 + wn * 64;
    float bv[4];
    #pragma unroll
    for (int ni = 0; ni < 4; ++ni) bv[ni] = bias[n0w + ni * 16 + l15];
    #pragma unroll
    for (int mi = 0; mi < 8; ++mi)
        #pragma unroll
        for (int reg = 0; reg < 4; ++reg) {
            const int mloc = mi * 16 + qd * 4 + reg;          // 0..127 within wave tile
            const int mg = m0 + wm * 128 + mloc;              // global row = k*64+b
            const float* qrow = q + (mloc & 63) * H_DIM;      // b = mg & 63 = mloc & 63
            float s2 = 0.f, sd = 0.f;
            #pragma unroll
            for (int ni = 0; ni < 4; ++ni) {
                const float y = acc[mi][ni][reg] + bv[ni];
                const float qv = qrow[n0w + ni * 16 + l15];
                s2 += y * y; sd += y * qv;
            }
            #pragma unroll
            for (int off = 1; off < 16; off <<= 1) {
                s2 += __shfl_xor(s2, off);
                sd += __shfl_xor(sd, off);
            }
            if (l15 == 0) {
                atomicAdd(&kn2[mg], s2);
                atomicAdd(&dots[mg], sd);
            }
        }
}

// ---- k4: per-b softmax + out = input + sum_k attn*kb.
// Reworked for occupancy/latency: 1024 thr/block (16 waves/CU), k split 4-way
// per block (64 loads/thread, combined via LDS) instead of 256 loads at 4 waves.
__global__ __launch_bounds__(1024) void final_kernel(
        const float* __restrict__ input, const u16* __restrict__ Kbf,
        const float* __restrict__ q, const float* __restrict__ kn2,
        const float* __restrict__ dots, float* __restrict__ out) {
    __shared__ float sm[K_DIM];
    __shared__ float buf[24];          // [0..15] qn partials, [16..19] mx, [20..23] se
    __shared__ float2 part[1024];      // [quarter*256 + col]
    const int b = blockIdx.x >> 2, hc = blockIdx.x & 3, tid = threadIdx.x;
    const int wave = tid >> 6, lane = tid & 63;
    // qn: sum q[b,:]^2 over 2048 elems, 2 per thread
    float s = 0.f;
    #pragma unroll
    for (int i = 0; i < 2; ++i) {
        float v = q[b * H_DIM + i * 1024 + tid];
        s += v * v;
    }
    #pragma unroll
    for (int o = 32; o >= 1; o >>= 1) s += __shfl_xor(s, o);
    if (lane == 0) buf[wave] = s;
    __syncthreads();
    float qs = 0.f;
    #pragma unroll
    for (int i = 0; i < 16; ++i) qs += buf[i];
    const float qn = fmaxf(sqrtf(qs), 1e-8f);
    __syncthreads();
    // scores + softmax over k (k == tid, first 4 waves)
    float sc = 0.f;
    if (tid < K_DIM) {
        const float kn = fmaxf(sqrtf(kn2[tid * B_DIM + b]), 1e-8f);
        sc = dots[tid * B_DIM + b] / (qn * kn);
        float mx = sc;
        #pragma unroll
        for (int o = 32; o >= 1; o >>= 1) mx = fmaxf(mx, __shfl_xor(mx, o));
        if (lane == 0) buf[16 + wave] = mx;
    }
    __syncthreads();
    const float mx = fmaxf(fmaxf(buf[16], buf[17]), fmaxf(buf[18], buf[19]));
    __syncthreads();
    if (tid < K_DIM) {
        const float e = expf(sc - mx);
        float se = e;
        #pragma unroll
        for (int o = 32; o >= 1; o >>= 1) se += __shfl_xor(se, o);
        if (lane == 0) buf[20 + wave] = se;
        sm[tid] = e;                   // normalized after se known
    }
    __syncthreads();
    const float sei = 1.f / (buf[20] + buf[21] + buf[22] + buf[23]);
    __syncthreads();
    // weighted sum: thread = (quarter, col); 64 k-iters each
    const int col = tid & 255, quarter = tid >> 8;
    const int h2 = hc * 256 + col;                 // u32 unit within row
    const u32* basep = (const u32*)Kbf + ((size_t)(quarter * 64 * B_DIM + b)) * (H_DIM / 2) + h2;
    const float* smq = sm + quarter * 64;
    float s0 = 0.f, s1 = 0.f;
    #pragma unroll 8
    for (int i = 0; i < 64; ++i) {
        const u32 p = basep[(size_t)i * (B_DIM * H_DIM / 2)];
        const float a = smq[i];
        s0 += a * __uint_as_float(p << 16);
        s1 += a * __uint_as_float(p & 0xffff0000u);
    }
    part[tid] = float2{s0, s1};
    __syncthreads();
    if (tid < 256) {
        float2 p0 = part[tid], p1 = part[256 + tid], p2 = part[512 + tid], p3 = part[768 + tid];
        const int h = h2 * 2;
        float2 iv = *(const float2*)&input[(size_t)b * H_DIM + h];
        float2 r;
        r.x = iv.x + (p0.x + p1.x + p2.x + p3.x) * sei;
        r.y = iv.y + (p0.y + p1.y + p2.y + p3.y) * sei;
        *(float2*)&out[(size_t)b * H_DIM + h] = r;
    }
}

extern "C" void kernel_launch(void* const* d_in, const int* in_sizes, int n_in,
                              void* d_out, int out_size, void* d_ws, size_t ws_size,
                              hipStream_t stream) {
    const float* input = (const float*)d_in[0];
    const float* kb    = (const float*)d_in[1];
    const float* W     = (const float*)d_in[2];
    const float* bias  = (const float*)d_in[3];
    float* out = (float*)d_out;
    char* ws = (char*)d_ws;

    u16*   Wb   = (u16*)(ws + WS_WBF);
    u16*   Aq   = (u16*)(ws + WS_AQ);
    float* q    = (float*)(ws + WS_Q);
    float* kn2  = (float*)(ws + WS_KN2);
    float* dots = (float*)(ws + WS_DOTS);
    u16*   Kbf  = (u16*)(ws + WS_KBF);

    static int lds_set = 0;
    if (!lds_set) {
        hipFuncSetAttribute((const void*)gemm_kernel,
                            hipFuncAttributeMaxDynamicSharedMemorySize, 131072);
        lds_set = 1;
    }

    prep_kernel<<<4096, NTHR, 0, stream>>>(W, input, bias, Wb, Aq, q, kn2, dots);
    mid_kernel<<<1024, NTHR, 0, stream>>>(kb, Aq, Wb, q, Kbf);
    gemm_kernel<<<512, 512, 131072, stream>>>(Kbf, Wb, bias, q, kn2, dots);
    final_kernel<<<256, 1024, 0, stream>>>(input, Kbf, q, kn2, dots, out);
}

// Round 5
// 362.084 us; speedup vs baseline: 1.0814x; 1.0138x over previous
//
#include <hip/hip_runtime.h>
#include <hip/hip_bf16.h>

typedef unsigned short u16;
typedef unsigned int u32;
typedef unsigned long long u64;
typedef __attribute__((ext_vector_type(8))) short short8;
typedef __attribute__((ext_vector_type(4))) float float4v;

#define B_DIM 64
#define H_DIM 2048
#define K_DIM 256
#define NTHR  256

// workspace layout (bytes)
#define WS_WBF   0ull                         // 2048*2048*2 = 8388608 (TILED)
#define WS_AQ    (8388608ull)                 // 128*2048*2  = 524288
#define WS_Q     (WS_AQ + 524288ull)          // 64*2048*4   = 524288
#define WS_KN2   (WS_Q + 524288ull)           // 16384*4
#define WS_DOTS  (WS_KN2 + 65536ull)          // 16384*4
#define WS_KBF   (WS_DOTS + 65536ull)         // 16384*2048*2 = 67108864 (TILED)

// ---- tiled bf16 layout (both Wb and Kbf) ----
// panel p (256 rows) x ktile t (32 cols): stream of 16B granules in EXACTLY the
// order gemm's global_load_lds consumes them, with the LDS XOR swizzle baked in:
// stream position (r, g) holds source granule g ^ ((r>>1)&3) of row p*256+r.
// => gemm staging is fully linear (1KB/instruction, dense 128B lines), and the
// proven read-side XOR (sw=(l15>>1)&3) still sees LDS[r][g]=G[r][g^((r>>1)&3)].
// u16 strides: panel=524288, tile=8192, row=32.

__device__ __forceinline__ u16 f2bf(float f) {
    unsigned int u = __float_as_uint(f);
    unsigned int r = (u + 0x7fffu + ((u >> 16) & 1u)) >> 16;
    return (u16)r;
}

__device__ __forceinline__ u64 pack4(float4v v) {
    u64 a0 = f2bf(v.x), a1 = f2bf(v.y), a2 = f2bf(v.z), a3 = f2bf(v.w);
    return a0 | (a1 << 16) | (a2 << 32) | (a3 << 48);
}

// async global->LDS 16B/lane; lds dest = wave-uniform base + lane*16
__device__ __forceinline__ void llds16(const u16* g, const u16* l) {
    __builtin_amdgcn_global_load_lds(
        (__attribute__((address_space(1))) void*)g,
        (__attribute__((address_space(3))) void*)l, 16, 0, 0);
}

// tiled-transform one 8-byte granule: out[go] <- packed source granule
__device__ __forceinline__ void tile_granule(const float* __restrict__ src,
                                             u64* __restrict__ dst, int go) {
    const int p   = go >> 17;          // 131072 8B-granules per panel
    const int rem = go & 131071;
    const int t   = rem >> 11;         // 2048 per ktile
    const int rr  = rem & 2047;
    const int r   = rr >> 3;           // 8 per row
    const int gg  = rr & 7;
    const int gs  = (((gg >> 1) ^ ((r >> 1) & 3)) << 3) + ((gg & 1) << 2);
    const float4v v = *(const float4v*)&src[((size_t)(p * 256 + r)) * H_DIM + t * 32 + gs];
    dst[go] = pack4(v);
}

// ---- gemm0 (q += in@W^T): 128-tile 2-barrier structure, 4-way split-K.
// A (Aq) raw layout; B (Wb) tiled layout.
__device__ __forceinline__ void gemm0_tile(const u16* __restrict__ Aq, const u16* __restrict__ Wb,
                                           float* __restrict__ qout, u16* As, u16* Bs,
                                           int nt, int ksplit) {
    const int tid = threadIdx.x;
    const int wave = tid >> 6, lane = tid & 63;
    const int l15 = lane & 15, qd = lane >> 4;
    const int wm = wave >> 1, wn = wave & 1;
    const int n0 = nt * 128;
    const int grow = lane >> 2;
    const int gcol = (((lane & 3) ^ ((lane >> 3) & 3)) * 8);
    const int sw = (l15 >> 1) & 3;
    // tiled Wb base for this 128-row half-panel
    const u16* wbase = Wb + (size_t)(nt >> 1) * 524288 + (size_t)((nt & 1) * 128) * 32
                          + (size_t)lane * 8;
    float4v acc[4][4] = {};
    const int kb0 = ksplit * 512;
    for (int kk = 0; kk < 16; ++kk) {
        const int k0 = kb0 + kk * 32;
        const int t = ksplit * 16 + kk;
        #pragma unroll
        for (int i = 0; i < 2; ++i) {
            const int r = wave * 32 + i * 16;
            llds16(wbase + (size_t)t * 8192 + (size_t)r * 32, &Bs[r * 32]);
            llds16(Aq + (size_t)(r + grow) * H_DIM + k0 + gcol, &As[r * 32]);
        }
        __syncthreads();
        short8 af[4], bf_[4];
        #pragma unroll
        for (int mi = 0; mi < 4; ++mi)
            af[mi] = *(const short8*)&As[(wm * 64 + mi * 16 + l15) * 32 + ((qd ^ sw) * 8)];
        #pragma unroll
        for (int ni = 0; ni < 4; ++ni)
            bf_[ni] = *(const short8*)&Bs[(wn * 64 + ni * 16 + l15) * 32 + ((qd ^ sw) * 8)];
        #pragma unroll
        for (int mi = 0; mi < 4; ++mi)
            #pragma unroll
            for (int ni = 0; ni < 4; ++ni)
                acc[mi][ni] = __builtin_amdgcn_mfma_f32_16x16x32_bf16(af[mi], bf_[ni], acc[mi][ni], 0, 0, 0);
        __syncthreads();
    }
    const int n0w = n0 + wn * 64;
    if (wm == 0) {
        #pragma unroll
        for (int mi = 0; mi < 4; ++mi)
            #pragma unroll
            for (int reg = 0; reg < 4; ++reg) {
                const int m = mi * 16 + qd * 4 + reg;   // 0..63 == b
                #pragma unroll
                for (int ni = 0; ni < 4; ++ni)
                    atomicAdd(&qout[m * H_DIM + n0w + ni * 16 + l15], acc[mi][ni][reg]);
            }
    }
}

// ---- k1: W->tiled bf16 + input->Aq + q=bias + zero kn2/dots (grid 4096) ----
__global__ __launch_bounds__(256) void prep_kernel(
        const float* __restrict__ W, const float* __restrict__ input,
        const float* __restrict__ bias, u16* __restrict__ Wb,
        u16* __restrict__ Aq, float* __restrict__ q,
        float* __restrict__ kn2, float* __restrict__ dots) {
    const int gid = blockIdx.x * NTHR + threadIdx.x;   // 0..1048575 == W 8B-granules
    tile_granule(W, (u64*)Wb, gid);
    if (gid < 65536) {
        u64 v = 0;
        if (gid < 32768) v = pack4(((const float4v*)input)[gid]);
        ((u64*)Aq)[gid] = v;
    }
    if (gid < 32768)
        ((float4v*)q)[gid] = ((const float4v*)bias)[gid & 511];
    if (gid < 4096) ((float4v*)kn2)[gid] = float4v{0.f, 0.f, 0.f, 0.f};
    else if (gid < 8192) ((float4v*)dots)[gid - 4096] = float4v{0.f, 0.f, 0.f, 0.f};
}

// ---- k2: blocks 0-63 gemm0 (split-K atomics); blocks 64+ kb->tiled bf16 ----
__global__ __launch_bounds__(256, 4) void mid_kernel(
        const float* __restrict__ kb, const u16* __restrict__ Aq,
        const u16* __restrict__ Wb, float* __restrict__ q, u16* __restrict__ Kbf) {
    __shared__ __align__(16) u16 As[128 * 32];
    __shared__ __align__(16) u16 Bs[128 * 32];
    const int bid = blockIdx.x;
    if (bid < 64) {
        gemm0_tile(Aq, Wb, q, As, Bs, bid & 15, bid >> 4);
    } else {
        u64* d8 = (u64*)Kbf;
        for (int go = (bid - 64) * NTHR + threadIdx.x; go < 8388608; go += 960 * NTHR)
            tile_granule(kb, d8, go);
    }
}

// ---- k3: big GEMM, 256x256 tile, BK=32, 8 waves (2M x 4N), 4-deep LDS ring.
// R2 schedule (best measured): 1 barrier/tile, counted lgkmcnt, cross-tile
// fragment prefetch, never vmcnt(0)/lgkm(0)-drain mid-loop. Staging now reads
// the TILED panels -> fully linear 1KB/instruction, dense lines.
#define TILE_BODY(T, bfC, a0C, bfN, a0N)                                        \
  {                                                                             \
    const int t_ = (T);                                                         \
    const u16* As_ = lds + (t_ & 3) * 16384;                                    \
    if (t_ + 3 < 64) stageA(t_ + 3);                                            \
    asm volatile("s_waitcnt lgkmcnt(0)" ::: "memory");                          \
    __builtin_amdgcn_sched_barrier(0);                                          \
    __builtin_amdgcn_s_setprio(1);                                              \
    _Pragma("unroll") for (int mi = 0; mi < 4; ++mi)                            \
      _Pragma("unroll") for (int ni = 0; ni < 4; ++ni)                          \
        acc[mi][ni] = __builtin_amdgcn_mfma_f32_16x16x32_bf16(a0C[mi], bfC[ni], acc[mi][ni], 0, 0, 0); \
    __builtin_amdgcn_s_setprio(0);                                              \
    __builtin_amdgcn_sched_barrier(0);                                          \
    _Pragma("unroll") for (int mi = 0; mi < 4; ++mi)                            \
        a0C[mi] = *(const short8*)&As_[aoff + (4 + mi) * 512];                  \
    if (t_ + 1 < 64) {                                                          \
      const u16* Asn_ = lds + ((t_ + 1) & 3) * 16384;                           \
      const u16* Bsn_ = Asn_ + 8192;                                            \
      _Pragma("unroll") for (int ni = 0; ni < 4; ++ni)                          \
          bfN[ni] = *(const short8*)&Bsn_[boff + ni * 512];                     \
      _Pragma("unroll") for (int mi = 0; mi < 4; ++mi)                          \
          a0N[mi] = *(const short8*)&Asn_[aoff + mi * 512];                     \
    }                                                                           \
    if (t_ + 3 < 64) stageB(t_ + 3);                                            \
    if (t_ + 1 < 64) { asm volatile("s_waitcnt lgkmcnt(8)" ::: "memory"); }     \
    else             { asm volatile("s_waitcnt lgkmcnt(0)" ::: "memory"); }     \
    __builtin_amdgcn_sched_barrier(0);                                          \
    __builtin_amdgcn_s_setprio(1);                                              \
    _Pragma("unroll") for (int mi = 0; mi < 4; ++mi)                            \
      _Pragma("unroll") for (int ni = 0; ni < 4; ++ni)                          \
        acc[4 + mi][ni] = __builtin_amdgcn_mfma_f32_16x16x32_bf16(a0C[mi], bfC[ni], acc[4 + mi][ni], 0, 0, 0); \
    __builtin_amdgcn_s_setprio(0);                                              \
    __builtin_amdgcn_sched_barrier(0);                                          \
    if (t_ <= 60) { asm volatile("s_waitcnt vmcnt(4)" ::: "memory"); }          \
    else          { asm volatile("s_waitcnt vmcnt(0)" ::: "memory"); }          \
    __builtin_amdgcn_s_barrier();                                               \
  }

__global__ __launch_bounds__(512, 2) void gemm_kernel(
        const u16* __restrict__ Kbf, const u16* __restrict__ Wb,
        const float* __restrict__ bias, const float* __restrict__ q,
        float* __restrict__ kn2, float* __restrict__ dots) {
    extern __shared__ __align__(16) u16 lds[];   // 4 slots x (A 8192 + B 8192) u16 = 128 KiB
    const int tid = threadIdx.x;
    const int wave = tid >> 6, lane = tid & 63;
    const int l15 = lane & 15, qd = lane >> 4;
    const int wm = wave >> 2, wn = wave & 3;
    const int nt = blockIdx.x & 7, mt = blockIdx.x >> 3;  // nt==XCD: B-panel L2-resident
    const int m0 = mt * 256, n0 = nt * 256;
    const int sw = (l15 >> 1) & 3;                        // read-side XOR swizzle

    // linear tiled sources (swizzle baked in at produce time)
    const u16* srcA = Kbf + (size_t)mt * 524288 + wave * 512 + lane * 8;
    const u16* srcB = Wb  + (size_t)nt * 524288 + wave * 512 + lane * 8;
    u16* dstBase = lds + wave * 512;                      // wave-uniform LDS dest base

    auto stageA = [&](int t) {
        u16* d = dstBase + (t & 3) * 16384;
        const u16* s = srcA + (size_t)t * 8192;
        llds16(s, d);                                     // rows 0..127
        llds16(s + 4096, d + 4096);                       // rows 128..255
    };
    auto stageB = [&](int t) {
        u16* d = dstBase + (t & 3) * 16384 + 8192;
        const u16* s = srcB + (size_t)t * 8192;
        llds16(s, d);
        llds16(s + 4096, d + 4096);
    };

    const int aoff = (wm * 128 + l15) * 32 + ((qd ^ sw) * 8);
    const int boff = (wn * 64 + l15) * 32 + ((qd ^ sw) * 8);

    float4v acc[8][4] = {};
    short8 bf0[4], a00[4], bf1[4], a01[4];

    // prologue: stage tiles 0,1,2; land 0,1; publish; preload tile-0 phase0 frags
    stageA(0); stageB(0); stageA(1); stageB(1); stageA(2); stageB(2);
    asm volatile("s_waitcnt vmcnt(4)" ::: "memory");      // tiles 0,1 landed
    __builtin_amdgcn_sched_barrier(0);
    __builtin_amdgcn_s_barrier();                         // publish slots 0,1
    {
        const u16* As0 = lds;
        const u16* Bs0 = lds + 8192;
        #pragma unroll
        for (int ni = 0; ni < 4; ++ni) bf0[ni] = *(const short8*)&Bs0[boff + ni * 512];
        #pragma unroll
        for (int mi = 0; mi < 4; ++mi) a00[mi] = *(const short8*)&As0[aoff + mi * 512];
    }

    for (int t = 0; t < 64; t += 2) {
        TILE_BODY(t,     bf0, a00, bf1, a01);
        TILE_BODY(t + 1, bf1, a01, bf0, a00);
    }

    // ---- fused epilogue: per-row sum(y^2), sum(y*q); cross-wave LDS reduce,
    // then ONE coalesced atomicAdd per row per array (was ~1M scattered atomics).
    const int n0w = n0 + wn * 64;
    float* red = (float*)lds;                  // [2][4 wn][256 rows] = 8 KB
    float bv[4];
    #pragma unroll
    for (int ni = 0; ni < 4; ++ni) bv[ni] = bias[n0w + ni * 16 + l15];
    #pragma unroll
    for (int mi = 0; mi < 8; ++mi)
        #pragma unroll
        for (int reg = 0; reg < 4; ++reg) {
            const int mloc = mi * 16 + qd * 4 + reg;          // 0..127 within wave tile
            const float* qrow = q + (mloc & 63) * H_DIM;      // b = mg & 63 = mloc & 63
            float s2 = 0.f, sd = 0.f;
            #pragma unroll
            for (int ni = 0; ni < 4; ++ni) {
                const float y = acc[mi][ni][reg] + bv[ni];
                const float qv = qrow[n0w + ni * 16 + l15];
                s2 += y * y; sd += y * qv;
            }
            #pragma unroll
            for (int off = 1; off < 16; off <<= 1) {
                s2 += __shfl_xor(s2, off);
                sd += __shfl_xor(sd, off);
            }
            if (l15 == 0) {
                const int row = wm * 128 + mloc;              // 0..255
                red[wn * 256 + row] = s2;
                red[1024 + wn * 256 + row] = sd;
            }
        }
    __syncthreads();
    if (tid < 256) {
        const float k2 = red[tid] + red[256 + tid] + red[512 + tid] + red[768 + tid];
        const float dd = red[1024 + tid] + red[1280 + tid] + red[1536 + tid] + red[1792 + tid];
        atomicAdd(&kn2[m0 + tid], k2);
        atomicAdd(&dots[m0 + tid], dd);
    }
}

// ---- k4: per-b softmax + out = input + sum_k attn*kb (kb read in fp32:
// coalesced, no Kbf dependency, better precision). 1024 thr, k split 4-way.
__global__ __launch_bounds__(1024) void final_kernel(
        const float* __restrict__ input, const float* __restrict__ kb,
        const float* __restrict__ q, const float* __restrict__ kn2,
        const float* __restrict__ dots, float* __restrict__ out) {
    __shared__ float sm[K_DIM];
    __shared__ float buf[24];          // [0..15] qn partials, [16..19] mx, [20..23] se
    __shared__ float2 part[1024];      // [quarter*256 + col]
    const int b = blockIdx.x >> 2, hc = blockIdx.x & 3, tid = threadIdx.x;
    const int wave = tid >> 6, lane = tid & 63;
    // qn: sum q[b,:]^2 over 2048 elems, 2 per thread
    float s = 0.f;
    #pragma unroll
    for (int i = 0; i < 2; ++i) {
        float v = q[b * H_DIM + i * 1024 + tid];
        s += v * v;
    }
    #pragma unroll
    for (int o = 32; o >= 1; o >>= 1) s += __shfl_xor(s, o);
    if (lane == 0) buf[wave] = s;
    __syncthreads();
    float qs = 0.f;
    #pragma unroll
    for (int i = 0; i < 16; ++i) qs += buf[i];
    const float qn = fmaxf(sqrtf(qs), 1e-8f);
    __syncthreads();
    // scores + softmax over k (k == tid, first 4 waves)
    float sc = 0.f;
    if (tid < K_DIM) {
        const float kn = fmaxf(sqrtf(kn2[tid * B_DIM + b]), 1e-8f);
        sc = dots[tid * B_DIM + b] / (qn * kn);
        float mx = sc;
        #pragma unroll
        for (int o = 32; o >= 1; o >>= 1) mx = fmaxf(mx, __shfl_xor(mx, o));
        if (lane == 0) buf[16 + wave] = mx;
    }
    __syncthreads();
    const float mx = fmaxf(fmaxf(buf[16], buf[17]), fmaxf(buf[18], buf[19]));
    __syncthreads();
    if (tid < K_DIM) {
        const float e = expf(sc - mx);
        float se = e;
        #pragma unroll
        for (int o = 32; o >= 1; o >>= 1) se += __shfl_xor(se, o);
        if (lane == 0) buf[20 + wave] = se;
        sm[tid] = e;                   // normalized after se known
    }
    __syncthreads();
    const float sei = 1.f / (buf[20] + buf[21] + buf[22] + buf[23]);
    __syncthreads();
    // weighted sum: thread = (quarter, col); 64 k-iters each, fp32 float2 loads
    const int col = tid & 255, quarter = tid >> 8;
    const int h2 = hc * 256 + col;                 // float2 unit within row
    const float2* basep = (const float2*)kb
        + ((size_t)(quarter * 64 * B_DIM + b)) * (H_DIM / 2) + h2;
    const float* smq = sm + quarter * 64;
    float s0 = 0.f, s1 = 0.f;
    #pragma unroll 8
    for (int i = 0; i < 64; ++i) {
        const float2 p = basep[(size_t)i * (B_DIM * H_DIM / 2)];
        const float a = smq[i];
        s0 += a * p.x;
        s1 += a * p.y;
    }
    part[tid] = float2{s0, s1};
    __syncthreads();
    if (tid < 256) {
        float2 p0 = part[tid], p1 = part[256 + tid], p2 = part[512 + tid], p3 = part[768 + tid];
        const int h = h2 * 2;
        float2 iv = *(const float2*)&input[(size_t)b * H_DIM + h];
        float2 r;
        r.x = iv.x + (p0.x + p1.x + p2.x + p3.x) * sei;
        r.y = iv.y + (p0.y + p1.y + p2.y + p3.y) * sei;
        *(float2*)&out[(size_t)b * H_DIM + h] = r;
    }
}

extern "C" void kernel_launch(void* const* d_in, const int* in_sizes, int n_in,
                              void* d_out, int out_size, void* d_ws, size_t ws_size,
                              hipStream_t stream) {
    const float* input = (const float*)d_in[0];
    const float* kb    = (const float*)d_in[1];
    const float* W     = (const float*)d_in[2];
    const float* bias  = (const float*)d_in[3];
    float* out = (float*)d_out;
    char* ws = (char*)d_ws;

    u16*   Wb   = (u16*)(ws + WS_WBF);
    u16*   Aq   = (u16*)(ws + WS_AQ);
    float* q    = (float*)(ws + WS_Q);
    float* kn2  = (float*)(ws + WS_KN2);
    float* dots = (float*)(ws + WS_DOTS);
    u16*   Kbf  = (u16*)(ws + WS_KBF);

    static int lds_set = 0;
    if (!lds_set) {
        hipFuncSetAttribute((const void*)gemm_kernel,
                            hipFuncAttributeMaxDynamicSharedMemorySize, 131072);
        lds_set = 1;
    }

    prep_kernel<<<4096, NTHR, 0, stream>>>(W, input, bias, Wb, Aq, q, kn2, dots);
    mid_kernel<<<1024, NTHR, 0, stream>>>(kb, Aq, Wb, q, Kbf);
    gemm_kernel<<<512, 512, 131072, stream>>>(Kbf, Wb, bias, q, kn2, dots);
    final_kernel<<<256, 1024, 0, stream>>>(input, kb, q, kn2, dots, out);
}